// Round 1
// baseline (6135.312 us; speedup 1.0000x reference)
//
#include <hip/hip_runtime.h>

// DKVMN forward, round 15 — all-VGPR state in kS.
// R14 (6200 µs) kept 8 of 16 rows/wave as fp16 in LDS because m[16] spilled at
// the compiler's default ~56-reg grant. But LDS=112KB already forced 1 block/CU
// (16 waves), so up to 128 VGPR/wave is legal: __launch_bounds__(1024, 4)
// raises the grant. R15: m[16] float4 = 64 VGPR state, s_m deleted (LDS 112->48
// KB), all per-step h2f/f2h conversions gone (~96 VALU/lane/step saved), LDS
// pipe per wave-step drops 22 -> ~6 instrs. Also: manual 1-step prefetch of the
// wave-uniform w scalar loads and of the e/a LDS tiles (only 4 waves/SIMD
// available to hide the s_load/ds_read head-of-chain latency).
//   kW: wtab[513][512] fp32   kG: etab/atab[1025][256] fp32   (3.2 MB, hot)
//   kS: 512 blocks (b x 2 chunks) x 1024 thr (16 waves x 16 rows x float4);
//       w via SGPR loads from wtab; e/a LDS tiles per 16 steps; r merged via
//       lane-plane LDS adds, drained as plain fp16 stores to 2 regions.
//   kM: MLP over all 131072 (b,t); sums the 2 fp16 partial regions.
// ws = 3.2 MB + 128 MiB.

#define B_ 256
#define T_ 512
#define N_ 512
#define DK_ 64
#define DV_ 256
#define S_ 64
#define NP_ (B_ * T_)
#define NCID 513
#define NIID 1025
#define TB_ 16

typedef _Float16 h16;
typedef __attribute__((ext_vector_type(4))) _Float16 half4;

__device__ __forceinline__ float dot4(float4 a, float4 b) {
  return a.x * b.x + a.y * b.y + a.z * b.z + a.w * b.w;
}
__device__ __forceinline__ float4 h2f(half4 h) {
  return make_float4((float)h.x, (float)h.y, (float)h.z, (float)h.w);
}
__device__ __forceinline__ half4 f2h(float4 f) {
  half4 h;
  h.x = (h16)f.x; h.y = (h16)f.y; h.z = (h16)f.z; h.w = (h16)f.w;
  return h;
}

// ============ kW: wtab[c][n] = softmax_n(q_c . K_n), 513 blocks ============
__global__ __launch_bounds__(512) void kW(const float* __restrict__ Kmem,
                                          const float* __restrict__ cemb,
                                          float* __restrict__ wtab) {
  __shared__ float s_q[DK_];
  __shared__ float s_red[16];
  const int tid = threadIdx.x, c = blockIdx.x;
  if (tid < DK_) s_q[tid] = c ? cemb[c * DK_ + tid] : 0.f;
  __syncthreads();
  const int n = tid;
  const float4* kr = (const float4*)(Kmem + n * DK_);
  float acc = 0.f;
#pragma unroll
  for (int kk = 0; kk < DK_ / 4; ++kk) acc += dot4(kr[kk], *(const float4*)&s_q[kk * 4]);
  const int lane = tid & 63, wid = tid >> 6;
  float mx = acc;
  for (int off = 32; off; off >>= 1) mx = fmaxf(mx, __shfl_xor(mx, off, 64));
  if (lane == 0) s_red[wid] = mx;
  __syncthreads();
  float gmx = s_red[0];
#pragma unroll
  for (int i = 1; i < 8; ++i) gmx = fmaxf(gmx, s_red[i]);
  const float e = expf(acc - gmx);
  float sum = e;
  for (int off = 32; off; off >>= 1) sum += __shfl_xor(sum, off, 64);
  if (lane == 0) s_red[8 + wid] = sum;
  __syncthreads();
  float gs = 0.f;
#pragma unroll
  for (int i = 0; i < 8; ++i) gs += s_red[8 + i];
  wtab[c * N_ + n] = e / gs;
}

// ============ kG: etab/atab[id][d], 129 blocks x 8 ids =====================
__global__ __launch_bounds__(512) void kG(const float* __restrict__ iemb,
                                          const float* __restrict__ We,
                                          const float* __restrict__ be,
                                          const float* __restrict__ Wa,
                                          const float* __restrict__ ba,
                                          float* __restrict__ etab,
                                          float* __restrict__ atab) {
  __shared__ float s_v[8 * DV_];
  const int tid = threadIdx.x, bi = blockIdx.x;
  {
    const int j = tid >> 6, c4 = tid & 63;
    const int id = bi * 8 + j;
    float4 v = make_float4(0.f, 0.f, 0.f, 0.f);
    if (id >= 1 && id < NIID) v = ((const float4*)iemb)[(size_t)id * 64 + c4];
    *(float4*)&s_v[j * DV_ + c4 * 4] = v;
  }
  __syncthreads();
  const int gate = tid >> 8, d = tid & 255;
  const float4* wr = (const float4*)((gate ? Wa : We) + d * DV_);
  float acc[8];
#pragma unroll
  for (int j = 0; j < 8; ++j) acc[j] = 0.f;
  for (int kk = 0; kk < DV_ / 4; ++kk) {
    const float4 w4 = wr[kk];
#pragma unroll
    for (int j = 0; j < 8; ++j) acc[j] += dot4(w4, *(const float4*)&s_v[j * DV_ + kk * 4]);
  }
  const float bias = gate ? ba[d] : be[d];
#pragma unroll
  for (int j = 0; j < 8; ++j) {
    const int id = bi * 8 + j;
    if (id < NIID) {
      if (gate) atab[(size_t)id * DV_ + d] = tanhf(acc[j] + bias);
      else      etab[(size_t)id * DV_ + d] = 1.f / (1.f + expf(-(acc[j] + bias)));
    }
  }
}

// ============ kS: all-VGPR recurrence, 512 blocks x 1024 thr ===============
// block = (b, ch in {0,1}); wave owns 16 rows, ALL in VGPRs (m[16] = 64 regs).
// __launch_bounds__(1024, 4): 4 waves/EU = this one 16-wave block per CU ->
// compiler may grant up to 128 VGPR/wave (default heuristic granted ~56 and
// forced the old fp16-LDS hybrid).
__global__ __launch_bounds__(1024, 4) void kS(
    const int* __restrict__ concepts, const int* __restrict__ inter,
    const float* __restrict__ Vmem, const float* __restrict__ wtab,
    const float* __restrict__ etab, const float* __restrict__ atab,
    h16* __restrict__ rpart) {
  __shared__ float s_e[TB_][DV_];     // 16 KB
  __shared__ float s_a[TB_][DV_];     // 16 KB
  __shared__ float s_rt[TB_][4][64];  // 16 KB, lane-indexed planes
  const int tid = threadIdx.x, bx = blockIdx.x;
  const int b = bx >> 1, ch = bx & 1;
  const int lane = tid & 63, wv = tid >> 6;  // 16 waves
  const int row0 = ch * 256 + __builtin_amdgcn_readfirstlane(wv * 16);
  float4 m[16];  // 64 VGPRs: rows row0..row0+15, fp32, resident all 512 steps
  {
    const float4* vm4 = (const float4*)Vmem;
#pragma unroll
    for (int i = 0; i < 16; ++i) m[i] = vm4[(size_t)(row0 + i) * 64 + lane];
  }
  const int* cb = concepts + b * T_;
  const int* ib = inter + b * T_;
  const float4* etab4 = (const float4*)etab;
  const float4* atab4 = (const float4*)atab;
  h16* rp = rpart + (size_t)ch * NP_ * DV_ + (size_t)b * T_ * DV_;

  // prefetch w for t=0 (wave-uniform -> SGPR loads)
  const float* wp0 = wtab + (size_t)cb[0] * N_ + row0;
  float4 w0 = *(const float4*)(wp0 + 0);
  float4 w1 = *(const float4*)(wp0 + 4);
  float4 w2 = *(const float4*)(wp0 + 8);
  float4 w3 = *(const float4*)(wp0 + 12);

  for (int t0 = 0; t0 < T_; t0 += TB_) {
    // ---- stage e/a tiles; zero r planes ----
#pragma unroll
    for (int i = 0; i < 2; ++i) {
      const int idx = tid + i * 1024;  // 0..2047 float4
      const int tl = idx >> 7, half = (idx >> 6) & 1, c4 = idx & 63;
      const int iv = ib[t0 + tl];
      if (half == 0)
        *(float4*)&s_e[tl][c4 * 4] = etab4[(size_t)iv * 64 + c4];
      else
        *(float4*)&s_a[tl][c4 * 4] = atab4[(size_t)iv * 64 + c4];
    }
    ((float4*)s_rt)[tid] = make_float4(0.f, 0.f, 0.f, 0.f);
    __syncthreads();

    // prime e/a for tl=0 of this tile
    float4 e4 = *(const float4*)&s_e[0][lane * 4];
    float4 a4 = *(const float4*)&s_a[0][lane * 4];

    // ---- 16 timesteps ----
    for (int tl = 0; tl < TB_; ++tl) {
      // prefetch next step's w (clamped uniform index -> SGPR loads issued
      // before this step's FMA chain)
      const int tn = t0 + tl + 1;
      const float* wpn = wtab + (size_t)cb[tn < T_ ? tn : T_ - 1] * N_ + row0;
      const float4 nw0 = *(const float4*)(wpn + 0);
      const float4 nw1 = *(const float4*)(wpn + 4);
      const float4 nw2 = *(const float4*)(wpn + 8);
      const float4 nw3 = *(const float4*)(wpn + 12);
      // prefetch next step's e/a ((tl+1)&15 is always a valid read; value is
      // discarded on the last step of the tile and re-primed after the barrier)
      const float4 en = *(const float4*)&s_e[(tl + 1) & (TB_ - 1)][lane * 4];
      const float4 an = *(const float4*)&s_a[(tl + 1) & (TB_ - 1)][lane * 4];

      float4 racc = make_float4(0.f, 0.f, 0.f, 0.f);
#pragma unroll
      for (int g = 0; g < 4; ++g) {
        const float4 wg = (g == 0) ? w0 : (g == 1) ? w1 : (g == 2) ? w2 : w3;
#pragma unroll
        for (int i = 0; i < 4; ++i) {
          const int r = g * 4 + i;
          const float w = (i == 0) ? wg.x : (i == 1) ? wg.y : (i == 2) ? wg.z : wg.w;
          racc.x = fmaf(w, m[r].x, racc.x);
          racc.y = fmaf(w, m[r].y, racc.y);
          racc.z = fmaf(w, m[r].z, racc.z);
          racc.w = fmaf(w, m[r].w, racc.w);
          m[r].x = fmaf(-w, fmaf(e4.x, m[r].x, -a4.x), m[r].x);
          m[r].y = fmaf(-w, fmaf(e4.y, m[r].y, -a4.y), m[r].y);
          m[r].z = fmaf(-w, fmaf(e4.z, m[r].z, -a4.z), m[r].z);
          m[r].w = fmaf(-w, fmaf(e4.w, m[r].w, -a4.w), m[r].w);
        }
      }
      // lane-indexed LDS adds: 64 distinct dword addresses per plane
      atomicAdd(&s_rt[tl][0][lane], racc.x);
      atomicAdd(&s_rt[tl][1][lane], racc.y);
      atomicAdd(&s_rt[tl][2][lane], racc.z);
      atomicAdd(&s_rt[tl][3][lane], racc.w);
      w0 = nw0; w1 = nw1; w2 = nw2; w3 = nw3;
      e4 = en; a4 = an;
    }
    __syncthreads();

    // ---- drain: plain fp16 stores to this chunk's own region ----
    {
      const int tl = tid >> 6, l = tid & 63;  // 16 x 64 = 1024
      const float4 v = make_float4(s_rt[tl][0][l], s_rt[tl][1][l],
                                   s_rt[tl][2][l], s_rt[tl][3][l]);
      *(half4*)(rp + (size_t)(t0 + tl) * DV_ + l * 4) = f2h(v);
    }
    __syncthreads();
  }
}

// ============ kM: MLP head, 2048 blocks x 512 thr ==========================
#define MP_ 64
__global__ __launch_bounds__(512) void kM(const int* __restrict__ concepts,
                                          const float* __restrict__ cemb,
                                          const h16* __restrict__ rpart,
                                          const float* __restrict__ W1,
                                          const float* __restrict__ b1,
                                          const float* __restrict__ W2,
                                          const float* __restrict__ b2,
                                          const float* __restrict__ W3,
                                          const float* __restrict__ b3,
                                          float* __restrict__ out) {
  __shared__ float s_f[MP_][DV_ + DK_];  // 80 KB
  __shared__ h16 s_W1[S_][324];          // 40.5 KB (padded)
  __shared__ float s_h1[8][8][S_];       // 16 KB
  __shared__ int s_c[MP_];
  const int tid = threadIdx.x, g = blockIdx.x;
  const int lane = tid & 63, wv = tid >> 6;
  if (tid < MP_) s_c[tid] = concepts[g * MP_ + tid];
  {
    const int j = tid >> 3, f0 = tid & 7;
    const float4* w1r = (const float4*)(W1 + j * 320);
#pragma unroll
    for (int i = 0; i < 10; ++i) {
      const int k4 = f0 + i * 8;
      *(half4*)&s_W1[j][k4 * 4] = f2h(w1r[k4]);
    }
  }
  __syncthreads();
  {
    const half4* p0 = (const half4*)rpart;
    const half4* p1 = p0 + (size_t)NP_ * 64;
#pragma unroll
    for (int i = 0; i < 8; ++i) {
      const int idx = tid + i * 512, p = idx >> 6, c4 = idx & 63;
      const size_t off = (size_t)(g * MP_ + p) * 64 + c4;
      const float4 v0 = h2f(p0[off]);
      const float4 v1 = h2f(p1[off]);
      *(float4*)&s_f[p][c4 * 4] =
          make_float4(v0.x + v1.x, v0.y + v1.y, v0.z + v1.z, v0.w + v1.w);
    }
    const float4* ce4 = (const float4*)cemb;
    const float4 z = make_float4(0.f, 0.f, 0.f, 0.f);
#pragma unroll
    for (int i = 0; i < 2; ++i) {
      const int idx = tid + i * 512, p = idx >> 4, k4 = idx & 15;
      const int c = s_c[p];
      *(float4*)&s_f[p][DV_ + k4 * 4] = c ? ce4[c * 16 + k4] : z;
    }
  }
  __syncthreads();
  const int j = lane;
  float acc[8];
  {
    const float b1j = b1[j];
#pragma unroll
    for (int p = 0; p < 8; ++p) acc[p] = b1j;
  }
  for (int k4 = 0; k4 < 80; ++k4) {
    const float4 w4 = h2f(*(const half4*)&s_W1[j][k4 * 4]);
#pragma unroll
    for (int p = 0; p < 8; ++p)
      acc[p] += dot4(w4, *(const float4*)&s_f[wv * 8 + p][k4 * 4]);
  }
#pragma unroll
  for (int p = 0; p < 8; ++p) s_h1[wv][p][j] = fmaxf(acc[p], 0.f);
  __syncthreads();
  {
    const float b2j = b2[j];
#pragma unroll
    for (int p = 0; p < 8; ++p) acc[p] = b2j;
  }
  const float4* w2r = (const float4*)(W2 + j * S_);
#pragma unroll
  for (int k4 = 0; k4 < S_ / 4; ++k4) {
    const float4 w4 = w2r[k4];
#pragma unroll
    for (int p = 0; p < 8; ++p)
      acc[p] += dot4(w4, *(const float4*)&s_h1[wv][p][k4 * 4]);
  }
  const float w3j = W3[j], b3v = b3[0];
#pragma unroll
  for (int p = 0; p < 8; ++p) {
    float pp = fmaxf(acc[p], 0.f) * w3j;
    for (int off = 32; off; off >>= 1) pp += __shfl_xor(pp, off, 64);
    if (lane == 0)
      out[g * MP_ + wv * 8 + p] = 1.f / (1.f + expf(-(pp + b3v)));
  }
}

extern "C" void kernel_launch(void* const* d_in, const int* in_sizes, int n_in,
                              void* d_out, int out_size, void* d_ws, size_t ws_size,
                              hipStream_t stream) {
  const int* concepts = (const int*)d_in[0];
  const int* interactions = (const int*)d_in[1];
  const float* Kmem = (const float*)d_in[2];
  const float* Vmem = (const float*)d_in[3];
  const float* cemb = (const float*)d_in[4];
  const float* iemb = (const float*)d_in[5];
  const float* We = (const float*)d_in[6];
  const float* be = (const float*)d_in[7];
  const float* Wa = (const float*)d_in[8];
  const float* ba = (const float*)d_in[9];
  const float* W1 = (const float*)d_in[10];
  const float* b1 = (const float*)d_in[11];
  const float* W2 = (const float*)d_in[12];
  const float* b2 = (const float*)d_in[13];
  const float* W3 = (const float*)d_in[14];
  const float* b3 = (const float*)d_in[15];
  float* out = (float*)d_out;

  const size_t sz_w = (size_t)NCID * N_ * 4;
  const size_t sz_e = (size_t)NIID * DV_ * 4;
  float* wtab = (float*)d_ws;
  float* etab = (float*)((char*)d_ws + sz_w);
  float* atab = (float*)((char*)d_ws + sz_w + sz_e);
  h16* rpart = (h16*)((char*)d_ws + sz_w + 2 * sz_e);  // 2 x 64 MiB

  kW<<<dim3(NCID), dim3(512), 0, stream>>>(Kmem, cemb, wtab);
  kG<<<dim3((NIID + 7) / 8), dim3(512), 0, stream>>>(iemb, We, be, Wa, ba, etab, atab);
  kS<<<dim3(B_ * 2), dim3(1024), 0, stream>>>(concepts, interactions, Vmem,
                                              wtab, etab, atab, rpart);
  kM<<<dim3(NP_ / MP_), dim3(512), 0, stream>>>(concepts, cemb, rpart,
                                                W1, b1, W2, b2, W3, b3, out);
}

// Round 2
// 6094.382 us; speedup vs baseline: 1.0067x; 1.0067x over previous
//
#include <hip/hip_runtime.h>

// DKVMN forward, round 16 — force the VGPR grant with amdgpu_waves_per_eu(4,4).
// R15 post-mortem: __launch_bounds__(1024, 4) only sets the MIN waves/EU; the
// allocator still targeted 8 waves/EU (56 VGPR) and spilled m[16] to scratch.
// Counters: VGPR_Count=56 (unchanged), VALUBusy 17%, HBM 0.4% — the 5.55 ms is
// scratch-spill L2 traffic (512 B/lane/step = ~4-6 ms at per-CU L2 share).
// R16: __attribute__((amdgpu_waves_per_eu(4,4))) pins occupancy to 4 waves/EU
// (exactly our one 16-wave block/CU) -> 128 VGPR/wave budget; m[16] (64 regs)
// + working set (~100 total) fits, zero spill.
//   kW: wtab[513][512] fp32   kG: etab/atab[1025][256] fp32   (3.2 MB, hot)
//   kS: 512 blocks (b x 2 chunks) x 1024 thr (16 waves x 16 rows x float4);
//       w via SGPR loads from wtab; e/a LDS tiles per 16 steps; r merged via
//       lane-plane LDS adds, drained as plain fp16 stores to 2 regions.
//   kM: MLP over all 131072 (b,t); sums the 2 fp16 partial regions.
// ws = 3.2 MB + 128 MiB.

#define B_ 256
#define T_ 512
#define N_ 512
#define DK_ 64
#define DV_ 256
#define S_ 64
#define NP_ (B_ * T_)
#define NCID 513
#define NIID 1025
#define TB_ 16

typedef _Float16 h16;
typedef __attribute__((ext_vector_type(4))) _Float16 half4;

__device__ __forceinline__ float dot4(float4 a, float4 b) {
  return a.x * b.x + a.y * b.y + a.z * b.z + a.w * b.w;
}
__device__ __forceinline__ float4 h2f(half4 h) {
  return make_float4((float)h.x, (float)h.y, (float)h.z, (float)h.w);
}
__device__ __forceinline__ half4 f2h(float4 f) {
  half4 h;
  h.x = (h16)f.x; h.y = (h16)f.y; h.z = (h16)f.z; h.w = (h16)f.w;
  return h;
}

// ============ kW: wtab[c][n] = softmax_n(q_c . K_n), 513 blocks ============
__global__ __launch_bounds__(512) void kW(const float* __restrict__ Kmem,
                                          const float* __restrict__ cemb,
                                          float* __restrict__ wtab) {
  __shared__ float s_q[DK_];
  __shared__ float s_red[16];
  const int tid = threadIdx.x, c = blockIdx.x;
  if (tid < DK_) s_q[tid] = c ? cemb[c * DK_ + tid] : 0.f;
  __syncthreads();
  const int n = tid;
  const float4* kr = (const float4*)(Kmem + n * DK_);
  float acc = 0.f;
#pragma unroll
  for (int kk = 0; kk < DK_ / 4; ++kk) acc += dot4(kr[kk], *(const float4*)&s_q[kk * 4]);
  const int lane = tid & 63, wid = tid >> 6;
  float mx = acc;
  for (int off = 32; off; off >>= 1) mx = fmaxf(mx, __shfl_xor(mx, off, 64));
  if (lane == 0) s_red[wid] = mx;
  __syncthreads();
  float gmx = s_red[0];
#pragma unroll
  for (int i = 1; i < 8; ++i) gmx = fmaxf(gmx, s_red[i]);
  const float e = expf(acc - gmx);
  float sum = e;
  for (int off = 32; off; off >>= 1) sum += __shfl_xor(sum, off, 64);
  if (lane == 0) s_red[8 + wid] = sum;
  __syncthreads();
  float gs = 0.f;
#pragma unroll
  for (int i = 0; i < 8; ++i) gs += s_red[8 + i];
  wtab[c * N_ + n] = e / gs;
}

// ============ kG: etab/atab[id][d], 129 blocks x 8 ids =====================
__global__ __launch_bounds__(512) void kG(const float* __restrict__ iemb,
                                          const float* __restrict__ We,
                                          const float* __restrict__ be,
                                          const float* __restrict__ Wa,
                                          const float* __restrict__ ba,
                                          float* __restrict__ etab,
                                          float* __restrict__ atab) {
  __shared__ float s_v[8 * DV_];
  const int tid = threadIdx.x, bi = blockIdx.x;
  {
    const int j = tid >> 6, c4 = tid & 63;
    const int id = bi * 8 + j;
    float4 v = make_float4(0.f, 0.f, 0.f, 0.f);
    if (id >= 1 && id < NIID) v = ((const float4*)iemb)[(size_t)id * 64 + c4];
    *(float4*)&s_v[j * DV_ + c4 * 4] = v;
  }
  __syncthreads();
  const int gate = tid >> 8, d = tid & 255;
  const float4* wr = (const float4*)((gate ? Wa : We) + d * DV_);
  float acc[8];
#pragma unroll
  for (int j = 0; j < 8; ++j) acc[j] = 0.f;
  for (int kk = 0; kk < DV_ / 4; ++kk) {
    const float4 w4 = wr[kk];
#pragma unroll
    for (int j = 0; j < 8; ++j) acc[j] += dot4(w4, *(const float4*)&s_v[j * DV_ + kk * 4]);
  }
  const float bias = gate ? ba[d] : be[d];
#pragma unroll
  for (int j = 0; j < 8; ++j) {
    const int id = bi * 8 + j;
    if (id < NIID) {
      if (gate) atab[(size_t)id * DV_ + d] = tanhf(acc[j] + bias);
      else      etab[(size_t)id * DV_ + d] = 1.f / (1.f + expf(-(acc[j] + bias)));
    }
  }
}

// ============ kS: all-VGPR recurrence, 512 blocks x 1024 thr ===============
// block = (b, ch in {0,1}); wave owns 16 rows, ALL in VGPRs (m[16] = 64 regs).
// amdgpu_waves_per_eu(4,4): pins occupancy to exactly 4 waves/EU (= the one
// 16-wave block/CU) so the allocator budget is 128 VGPR/wave -> no spill.
__global__ __launch_bounds__(1024)
__attribute__((amdgpu_waves_per_eu(4, 4))) void kS(
    const int* __restrict__ concepts, const int* __restrict__ inter,
    const float* __restrict__ Vmem, const float* __restrict__ wtab,
    const float* __restrict__ etab, const float* __restrict__ atab,
    h16* __restrict__ rpart) {
  __shared__ float s_e[TB_][DV_];     // 16 KB
  __shared__ float s_a[TB_][DV_];     // 16 KB
  __shared__ float s_rt[TB_][4][64];  // 16 KB, lane-indexed planes
  const int tid = threadIdx.x, bx = blockIdx.x;
  const int b = bx >> 1, ch = bx & 1;
  const int lane = tid & 63, wv = tid >> 6;  // 16 waves
  const int row0 = ch * 256 + __builtin_amdgcn_readfirstlane(wv * 16);
  float4 m[16];  // 64 VGPRs: rows row0..row0+15, fp32, resident all 512 steps
  {
    const float4* vm4 = (const float4*)Vmem;
#pragma unroll
    for (int i = 0; i < 16; ++i) m[i] = vm4[(size_t)(row0 + i) * 64 + lane];
  }
  const int* cb = concepts + b * T_;
  const int* ib = inter + b * T_;
  const float4* etab4 = (const float4*)etab;
  const float4* atab4 = (const float4*)atab;
  h16* rp = rpart + (size_t)ch * NP_ * DV_ + (size_t)b * T_ * DV_;

  // prefetch w for t=0 (wave-uniform -> SGPR loads)
  const float* wp0 = wtab + (size_t)cb[0] * N_ + row0;
  float4 w0 = *(const float4*)(wp0 + 0);
  float4 w1 = *(const float4*)(wp0 + 4);
  float4 w2 = *(const float4*)(wp0 + 8);
  float4 w3 = *(const float4*)(wp0 + 12);

  for (int t0 = 0; t0 < T_; t0 += TB_) {
    // ---- stage e/a tiles; zero r planes ----
#pragma unroll
    for (int i = 0; i < 2; ++i) {
      const int idx = tid + i * 1024;  // 0..2047 float4
      const int tl = idx >> 7, half = (idx >> 6) & 1, c4 = idx & 63;
      const int iv = ib[t0 + tl];
      if (half == 0)
        *(float4*)&s_e[tl][c4 * 4] = etab4[(size_t)iv * 64 + c4];
      else
        *(float4*)&s_a[tl][c4 * 4] = atab4[(size_t)iv * 64 + c4];
    }
    ((float4*)s_rt)[tid] = make_float4(0.f, 0.f, 0.f, 0.f);
    __syncthreads();

    // prime e/a for tl=0 of this tile
    float4 e4 = *(const float4*)&s_e[0][lane * 4];
    float4 a4 = *(const float4*)&s_a[0][lane * 4];

    // ---- 16 timesteps ----
    for (int tl = 0; tl < TB_; ++tl) {
      // prefetch next step's w (clamped uniform index -> SGPR loads issued
      // before this step's FMA chain)
      const int tn = t0 + tl + 1;
      const float* wpn = wtab + (size_t)cb[tn < T_ ? tn : T_ - 1] * N_ + row0;
      const float4 nw0 = *(const float4*)(wpn + 0);
      const float4 nw1 = *(const float4*)(wpn + 4);
      const float4 nw2 = *(const float4*)(wpn + 8);
      const float4 nw3 = *(const float4*)(wpn + 12);
      // prefetch next step's e/a ((tl+1)&15 is always a valid read; value is
      // discarded on the last step of the tile and re-primed after the barrier)
      const float4 en = *(const float4*)&s_e[(tl + 1) & (TB_ - 1)][lane * 4];
      const float4 an = *(const float4*)&s_a[(tl + 1) & (TB_ - 1)][lane * 4];

      float4 racc = make_float4(0.f, 0.f, 0.f, 0.f);
#pragma unroll
      for (int g = 0; g < 4; ++g) {
        const float4 wg = (g == 0) ? w0 : (g == 1) ? w1 : (g == 2) ? w2 : w3;
#pragma unroll
        for (int i = 0; i < 4; ++i) {
          const int r = g * 4 + i;
          const float w = (i == 0) ? wg.x : (i == 1) ? wg.y : (i == 2) ? wg.z : wg.w;
          racc.x = fmaf(w, m[r].x, racc.x);
          racc.y = fmaf(w, m[r].y, racc.y);
          racc.z = fmaf(w, m[r].z, racc.z);
          racc.w = fmaf(w, m[r].w, racc.w);
          m[r].x = fmaf(-w, fmaf(e4.x, m[r].x, -a4.x), m[r].x);
          m[r].y = fmaf(-w, fmaf(e4.y, m[r].y, -a4.y), m[r].y);
          m[r].z = fmaf(-w, fmaf(e4.z, m[r].z, -a4.z), m[r].z);
          m[r].w = fmaf(-w, fmaf(e4.w, m[r].w, -a4.w), m[r].w);
        }
      }
      // lane-indexed LDS adds: 64 distinct dword addresses per plane
      atomicAdd(&s_rt[tl][0][lane], racc.x);
      atomicAdd(&s_rt[tl][1][lane], racc.y);
      atomicAdd(&s_rt[tl][2][lane], racc.z);
      atomicAdd(&s_rt[tl][3][lane], racc.w);
      w0 = nw0; w1 = nw1; w2 = nw2; w3 = nw3;
      e4 = en; a4 = an;
    }
    __syncthreads();

    // ---- drain: plain fp16 stores to this chunk's own region ----
    {
      const int tl = tid >> 6, l = tid & 63;  // 16 x 64 = 1024
      const float4 v = make_float4(s_rt[tl][0][l], s_rt[tl][1][l],
                                   s_rt[tl][2][l], s_rt[tl][3][l]);
      *(half4*)(rp + (size_t)(t0 + tl) * DV_ + l * 4) = f2h(v);
    }
    __syncthreads();
  }
}

// ============ kM: MLP head, 2048 blocks x 512 thr ==========================
#define MP_ 64
__global__ __launch_bounds__(512) void kM(const int* __restrict__ concepts,
                                          const float* __restrict__ cemb,
                                          const h16* __restrict__ rpart,
                                          const float* __restrict__ W1,
                                          const float* __restrict__ b1,
                                          const float* __restrict__ W2,
                                          const float* __restrict__ b2,
                                          const float* __restrict__ W3,
                                          const float* __restrict__ b3,
                                          float* __restrict__ out) {
  __shared__ float s_f[MP_][DV_ + DK_];  // 80 KB
  __shared__ h16 s_W1[S_][324];          // 40.5 KB (padded)
  __shared__ float s_h1[8][8][S_];       // 16 KB
  __shared__ int s_c[MP_];
  const int tid = threadIdx.x, g = blockIdx.x;
  const int lane = tid & 63, wv = tid >> 6;
  if (tid < MP_) s_c[tid] = concepts[g * MP_ + tid];
  {
    const int j = tid >> 3, f0 = tid & 7;
    const float4* w1r = (const float4*)(W1 + j * 320);
#pragma unroll
    for (int i = 0; i < 10; ++i) {
      const int k4 = f0 + i * 8;
      *(half4*)&s_W1[j][k4 * 4] = f2h(w1r[k4]);
    }
  }
  __syncthreads();
  {
    const half4* p0 = (const half4*)rpart;
    const half4* p1 = p0 + (size_t)NP_ * 64;
#pragma unroll
    for (int i = 0; i < 8; ++i) {
      const int idx = tid + i * 512, p = idx >> 6, c4 = idx & 63;
      const size_t off = (size_t)(g * MP_ + p) * 64 + c4;
      const float4 v0 = h2f(p0[off]);
      const float4 v1 = h2f(p1[off]);
      *(float4*)&s_f[p][c4 * 4] =
          make_float4(v0.x + v1.x, v0.y + v1.y, v0.z + v1.z, v0.w + v1.w);
    }
    const float4* ce4 = (const float4*)cemb;
    const float4 z = make_float4(0.f, 0.f, 0.f, 0.f);
#pragma unroll
    for (int i = 0; i < 2; ++i) {
      const int idx = tid + i * 512, p = idx >> 4, k4 = idx & 15;
      const int c = s_c[p];
      *(float4*)&s_f[p][DV_ + k4 * 4] = c ? ce4[c * 16 + k4] : z;
    }
  }
  __syncthreads();
  const int j = lane;
  float acc[8];
  {
    const float b1j = b1[j];
#pragma unroll
    for (int p = 0; p < 8; ++p) acc[p] = b1j;
  }
  for (int k4 = 0; k4 < 80; ++k4) {
    const float4 w4 = h2f(*(const half4*)&s_W1[j][k4 * 4]);
#pragma unroll
    for (int p = 0; p < 8; ++p)
      acc[p] += dot4(w4, *(const float4*)&s_f[wv * 8 + p][k4 * 4]);
  }
#pragma unroll
  for (int p = 0; p < 8; ++p) s_h1[wv][p][j] = fmaxf(acc[p], 0.f);
  __syncthreads();
  {
    const float b2j = b2[j];
#pragma unroll
    for (int p = 0; p < 8; ++p) acc[p] = b2j;
  }
  const float4* w2r = (const float4*)(W2 + j * S_);
#pragma unroll
  for (int k4 = 0; k4 < S_ / 4; ++k4) {
    const float4 w4 = w2r[k4];
#pragma unroll
    for (int p = 0; p < 8; ++p)
      acc[p] += dot4(w4, *(const float4*)&s_h1[wv][p][k4 * 4]);
  }
  const float w3j = W3[j], b3v = b3[0];
#pragma unroll
  for (int p = 0; p < 8; ++p) {
    float pp = fmaxf(acc[p], 0.f) * w3j;
    for (int off = 32; off; off >>= 1) pp += __shfl_xor(pp, off, 64);
    if (lane == 0)
      out[g * MP_ + wv * 8 + p] = 1.f / (1.f + expf(-(pp + b3v)));
  }
}

extern "C" void kernel_launch(void* const* d_in, const int* in_sizes, int n_in,
                              void* d_out, int out_size, void* d_ws, size_t ws_size,
                              hipStream_t stream) {
  const int* concepts = (const int*)d_in[0];
  const int* interactions = (const int*)d_in[1];
  const float* Kmem = (const float*)d_in[2];
  const float* Vmem = (const float*)d_in[3];
  const float* cemb = (const float*)d_in[4];
  const float* iemb = (const float*)d_in[5];
  const float* We = (const float*)d_in[6];
  const float* be = (const float*)d_in[7];
  const float* Wa = (const float*)d_in[8];
  const float* ba = (const float*)d_in[9];
  const float* W1 = (const float*)d_in[10];
  const float* b1 = (const float*)d_in[11];
  const float* W2 = (const float*)d_in[12];
  const float* b2 = (const float*)d_in[13];
  const float* W3 = (const float*)d_in[14];
  const float* b3 = (const float*)d_in[15];
  float* out = (float*)d_out;

  const size_t sz_w = (size_t)NCID * N_ * 4;
  const size_t sz_e = (size_t)NIID * DV_ * 4;
  float* wtab = (float*)d_ws;
  float* etab = (float*)((char*)d_ws + sz_w);
  float* atab = (float*)((char*)d_ws + sz_w + sz_e);
  h16* rpart = (h16*)((char*)d_ws + sz_w + 2 * sz_e);  // 2 x 64 MiB

  kW<<<dim3(NCID), dim3(512), 0, stream>>>(Kmem, cemb, wtab);
  kG<<<dim3((NIID + 7) / 8), dim3(512), 0, stream>>>(iemb, We, be, Wa, ba, etab, atab);
  kS<<<dim3(B_ * 2), dim3(1024), 0, stream>>>(concepts, interactions, Vmem,
                                              wtab, etab, atab, rpart);
  kM<<<dim3(NP_ / MP_), dim3(512), 0, stream>>>(concepts, cemb, rpart,
                                                W1, b1, W2, b2, W3, b3, out);
}

// Round 3
// 3386.155 us; speedup vs baseline: 1.8119x; 1.7998x over previous
//
#include <hip/hip_runtime.h>

// DKVMN forward, round 17 — atomic-free, SMEM-free step loop in kS.
// R14/R15/R16 all measured ~5.55 ms for kS despite totally different state
// storage (fp16-LDS hybrid / "spilled" m[16] / pinned-waves m[16]) -> state
// location is NOT the bottleneck (gfx950 unified VGPR/AGPR file parks m[16]
// in AGPRs; VGPR_Count=56 is arch-only). VALUBusy 17% = ~0.9 ms of VALU issue
// over 5.55 ms: waves stall ~83% of each step. The shared-by-all-rounds
// suspects are the per-step merge machinery:
//   (a) 4 LDS atomicAdds x 16 waves colliding on the same 256 addresses
//       (cross-wave same-address RMW serialization), and
//   (b) per-step SMEM s_loads of w mixed with DS ops: SMEM returns out of
//       order, so every consumer forces s_waitcnt lgkmcnt(0), draining the
//       whole LDS/atomic queue every step.
// R17 removes both: w is pre-staged per 16-step tile into LDS (s_w, loaded
// cooperatively with e/a via VMEM), read per-step as broadcast ds_read_b128;
// the r merge is a plain ds_write_b128 to a per-wave slot (s_racc, 64 KB)
// reduced every 4 steps by 256 threads and stored as fp16. The hot loop is
// pure DS+VALU -> compiler emits fine-grained lgkmcnt(N), no atomics.
//   kW: wtab[513][512] fp32   kG: etab/atab[1025][256] fp32   (3.2 MB, hot)
//   kS: 512 blocks (b x 2 chunks) x 1024 thr (16 waves x 16 rows x float4);
//       LDS 112 KB: s_w/s_e/s_a 48 KB + s_racc 64 KB; 1 block/CU.
//   kM: MLP over all 131072 (b,t); sums the 2 fp16 partial regions.
// ws = 3.2 MB + 128 MiB.

#define B_ 256
#define T_ 512
#define N_ 512
#define DK_ 64
#define DV_ 256
#define S_ 64
#define NP_ (B_ * T_)
#define NCID 513
#define NIID 1025
#define TB_ 16

typedef _Float16 h16;
typedef __attribute__((ext_vector_type(4))) _Float16 half4;

__device__ __forceinline__ float dot4(float4 a, float4 b) {
  return a.x * b.x + a.y * b.y + a.z * b.z + a.w * b.w;
}
__device__ __forceinline__ float4 h2f(half4 h) {
  return make_float4((float)h.x, (float)h.y, (float)h.z, (float)h.w);
}
__device__ __forceinline__ half4 f2h(float4 f) {
  half4 h;
  h.x = (h16)f.x; h.y = (h16)f.y; h.z = (h16)f.z; h.w = (h16)f.w;
  return h;
}

// ============ kW: wtab[c][n] = softmax_n(q_c . K_n), 513 blocks ============
__global__ __launch_bounds__(512) void kW(const float* __restrict__ Kmem,
                                          const float* __restrict__ cemb,
                                          float* __restrict__ wtab) {
  __shared__ float s_q[DK_];
  __shared__ float s_red[16];
  const int tid = threadIdx.x, c = blockIdx.x;
  if (tid < DK_) s_q[tid] = c ? cemb[c * DK_ + tid] : 0.f;
  __syncthreads();
  const int n = tid;
  const float4* kr = (const float4*)(Kmem + n * DK_);
  float acc = 0.f;
#pragma unroll
  for (int kk = 0; kk < DK_ / 4; ++kk) acc += dot4(kr[kk], *(const float4*)&s_q[kk * 4]);
  const int lane = tid & 63, wid = tid >> 6;
  float mx = acc;
  for (int off = 32; off; off >>= 1) mx = fmaxf(mx, __shfl_xor(mx, off, 64));
  if (lane == 0) s_red[wid] = mx;
  __syncthreads();
  float gmx = s_red[0];
#pragma unroll
  for (int i = 1; i < 8; ++i) gmx = fmaxf(gmx, s_red[i]);
  const float e = expf(acc - gmx);
  float sum = e;
  for (int off = 32; off; off >>= 1) sum += __shfl_xor(sum, off, 64);
  if (lane == 0) s_red[8 + wid] = sum;
  __syncthreads();
  float gs = 0.f;
#pragma unroll
  for (int i = 0; i < 8; ++i) gs += s_red[8 + i];
  wtab[c * N_ + n] = e / gs;
}

// ============ kG: etab/atab[id][d], 129 blocks x 8 ids =====================
__global__ __launch_bounds__(512) void kG(const float* __restrict__ iemb,
                                          const float* __restrict__ We,
                                          const float* __restrict__ be,
                                          const float* __restrict__ Wa,
                                          const float* __restrict__ ba,
                                          float* __restrict__ etab,
                                          float* __restrict__ atab) {
  __shared__ float s_v[8 * DV_];
  const int tid = threadIdx.x, bi = blockIdx.x;
  {
    const int j = tid >> 6, c4 = tid & 63;
    const int id = bi * 8 + j;
    float4 v = make_float4(0.f, 0.f, 0.f, 0.f);
    if (id >= 1 && id < NIID) v = ((const float4*)iemb)[(size_t)id * 64 + c4];
    *(float4*)&s_v[j * DV_ + c4 * 4] = v;
  }
  __syncthreads();
  const int gate = tid >> 8, d = tid & 255;
  const float4* wr = (const float4*)((gate ? Wa : We) + d * DV_);
  float acc[8];
#pragma unroll
  for (int j = 0; j < 8; ++j) acc[j] = 0.f;
  for (int kk = 0; kk < DV_ / 4; ++kk) {
    const float4 w4 = wr[kk];
#pragma unroll
    for (int j = 0; j < 8; ++j) acc[j] += dot4(w4, *(const float4*)&s_v[j * DV_ + kk * 4]);
  }
  const float bias = gate ? ba[d] : be[d];
#pragma unroll
  for (int j = 0; j < 8; ++j) {
    const int id = bi * 8 + j;
    if (id < NIID) {
      if (gate) atab[(size_t)id * DV_ + d] = tanhf(acc[j] + bias);
      else      etab[(size_t)id * DV_ + d] = 1.f / (1.f + expf(-(acc[j] + bias)));
    }
  }
}

// ============ kS: pure DS+VALU recurrence, 512 blocks x 1024 thr ===========
// block = (b, ch in {0,1}); wave owns 16 rows in registers (m[16] = 64 regs,
// AGPR-backed is fine on gfx950's unified file).
__global__ __launch_bounds__(1024)
__attribute__((amdgpu_waves_per_eu(4, 4))) void kS(
    const int* __restrict__ concepts, const int* __restrict__ inter,
    const float* __restrict__ Vmem, const float* __restrict__ wtab,
    const float* __restrict__ etab, const float* __restrict__ atab,
    h16* __restrict__ rpart) {
  __shared__ float s_w[TB_][DV_];        // 16 KB: w[t][block's 256-row chunk]
  __shared__ float s_e[TB_][DV_];        // 16 KB
  __shared__ float s_a[TB_][DV_];        // 16 KB
  __shared__ float s_racc[4][16][DV_];   // 64 KB: 4 steps x 16 wave-partials
  const int tid = threadIdx.x, bx = blockIdx.x;
  const int b = bx >> 1, ch = bx & 1;
  const int lane = tid & 63, wv = tid >> 6;  // 16 waves
  const int row0 = ch * 256 + __builtin_amdgcn_readfirstlane(wv * 16);
  float4 m[16];  // rows row0..row0+15, fp32, resident all 512 steps
  {
    const float4* vm4 = (const float4*)Vmem;
#pragma unroll
    for (int i = 0; i < 16; ++i) m[i] = vm4[(size_t)(row0 + i) * 64 + lane];
  }
  const int* cb = concepts + b * T_;
  const int* ib = inter + b * T_;
  const float4* wtab4 = (const float4*)wtab;
  const float4* etab4 = (const float4*)etab;
  const float4* atab4 = (const float4*)atab;
  h16* rp = rpart + (size_t)ch * NP_ * DV_ + (size_t)b * T_ * DV_;

  // cooperative tile staging: w rows for 16 steps (block's 256-col chunk),
  // e/a rows for 16 steps. 3 float4 VMEM loads per thread, L2-resident tables.
  auto stage = [&](int t0) {
    const int tl = tid >> 6, c4 = tid & 63;
    const int cv = cb[t0 + tl];
    const int iv = ib[t0 + tl];
    *(float4*)&s_w[tl][c4 * 4] = wtab4[(size_t)cv * 128 + ch * 64 + c4];
    *(float4*)&s_e[tl][c4 * 4] = etab4[(size_t)iv * 64 + c4];
    *(float4*)&s_a[tl][c4 * 4] = atab4[(size_t)iv * 64 + c4];
  };

  stage(0);
  __syncthreads();

  for (int t0 = 0; t0 < T_; t0 += TB_) {
    for (int s = 0; s < 4; ++s) {  // 4 sub-tiles of 4 steps
#pragma unroll
      for (int j = 0; j < 4; ++j) {
        const int tl = s * 4 + j;
        // wave-uniform broadcast reads: this wave's 16 w values
        const float* wrow = &s_w[tl][wv * 16];
        const float4 wq0 = *(const float4*)(wrow + 0);
        const float4 wq1 = *(const float4*)(wrow + 4);
        const float4 wq2 = *(const float4*)(wrow + 8);
        const float4 wq3 = *(const float4*)(wrow + 12);
        const float4 e4 = *(const float4*)&s_e[tl][lane * 4];
        const float4 a4 = *(const float4*)&s_a[tl][lane * 4];
        float4 racc = make_float4(0.f, 0.f, 0.f, 0.f);
#pragma unroll
        for (int g = 0; g < 4; ++g) {
          const float4 wg = (g == 0) ? wq0 : (g == 1) ? wq1 : (g == 2) ? wq2 : wq3;
#pragma unroll
          for (int i = 0; i < 4; ++i) {
            const int r = g * 4 + i;
            const float w = (i == 0) ? wg.x : (i == 1) ? wg.y : (i == 2) ? wg.z : wg.w;
            racc.x = fmaf(w, m[r].x, racc.x);
            racc.y = fmaf(w, m[r].y, racc.y);
            racc.z = fmaf(w, m[r].z, racc.z);
            racc.w = fmaf(w, m[r].w, racc.w);
            m[r].x = fmaf(-w, fmaf(e4.x, m[r].x, -a4.x), m[r].x);
            m[r].y = fmaf(-w, fmaf(e4.y, m[r].y, -a4.y), m[r].y);
            m[r].z = fmaf(-w, fmaf(e4.z, m[r].z, -a4.z), m[r].z);
            m[r].w = fmaf(-w, fmaf(e4.w, m[r].w, -a4.w), m[r].w);
          }
        }
        // plain per-wave partial write — no atomics
        *(float4*)&s_racc[j][wv][lane * 4] = racc;
      }
      __syncthreads();
      // overlap next-tile staging with the drain (independent LDS regions)
      if (s == 3 && t0 + TB_ < T_) stage(t0 + TB_);
      if (tid < 256) {  // 4 waves: reduce 16 wave-partials, store fp16
        const int j = tid >> 6, l = tid & 63;
        float4 acc = make_float4(0.f, 0.f, 0.f, 0.f);
#pragma unroll
        for (int w2 = 0; w2 < 16; ++w2) {
          const float4 v = *(const float4*)&s_racc[j][w2][l * 4];
          acc.x += v.x; acc.y += v.y; acc.z += v.z; acc.w += v.w;
        }
        *(half4*)(rp + (size_t)(t0 + s * 4 + j) * DV_ + l * 4) = f2h(acc);
      }
      __syncthreads();
    }
  }
}

// ============ kM: MLP head, 2048 blocks x 512 thr ==========================
#define MP_ 64
__global__ __launch_bounds__(512) void kM(const int* __restrict__ concepts,
                                          const float* __restrict__ cemb,
                                          const h16* __restrict__ rpart,
                                          const float* __restrict__ W1,
                                          const float* __restrict__ b1,
                                          const float* __restrict__ W2,
                                          const float* __restrict__ b2,
                                          const float* __restrict__ W3,
                                          const float* __restrict__ b3,
                                          float* __restrict__ out) {
  __shared__ float s_f[MP_][DV_ + DK_];  // 80 KB
  __shared__ h16 s_W1[S_][324];          // 40.5 KB (padded)
  __shared__ float s_h1[8][8][S_];       // 16 KB
  __shared__ int s_c[MP_];
  const int tid = threadIdx.x, g = blockIdx.x;
  const int lane = tid & 63, wv = tid >> 6;
  if (tid < MP_) s_c[tid] = concepts[g * MP_ + tid];
  {
    const int j = tid >> 3, f0 = tid & 7;
    const float4* w1r = (const float4*)(W1 + j * 320);
#pragma unroll
    for (int i = 0; i < 10; ++i) {
      const int k4 = f0 + i * 8;
      *(half4*)&s_W1[j][k4 * 4] = f2h(w1r[k4]);
    }
  }
  __syncthreads();
  {
    const half4* p0 = (const half4*)rpart;
    const half4* p1 = p0 + (size_t)NP_ * 64;
#pragma unroll
    for (int i = 0; i < 8; ++i) {
      const int idx = tid + i * 512, p = idx >> 6, c4 = idx & 63;
      const size_t off = (size_t)(g * MP_ + p) * 64 + c4;
      const float4 v0 = h2f(p0[off]);
      const float4 v1 = h2f(p1[off]);
      *(float4*)&s_f[p][c4 * 4] =
          make_float4(v0.x + v1.x, v0.y + v1.y, v0.z + v1.z, v0.w + v1.w);
    }
    const float4* ce4 = (const float4*)cemb;
    const float4 z = make_float4(0.f, 0.f, 0.f, 0.f);
#pragma unroll
    for (int i = 0; i < 2; ++i) {
      const int idx = tid + i * 512, p = idx >> 4, k4 = idx & 15;
      const int c = s_c[p];
      *(float4*)&s_f[p][DV_ + k4 * 4] = c ? ce4[c * 16 + k4] : z;
    }
  }
  __syncthreads();
  const int j = lane;
  float acc[8];
  {
    const float b1j = b1[j];
#pragma unroll
    for (int p = 0; p < 8; ++p) acc[p] = b1j;
  }
  for (int k4 = 0; k4 < 80; ++k4) {
    const float4 w4 = h2f(*(const half4*)&s_W1[j][k4 * 4]);
#pragma unroll
    for (int p = 0; p < 8; ++p)
      acc[p] += dot4(w4, *(const float4*)&s_f[wv * 8 + p][k4 * 4]);
  }
#pragma unroll
  for (int p = 0; p < 8; ++p) s_h1[wv][p][j] = fmaxf(acc[p], 0.f);
  __syncthreads();
  {
    const float b2j = b2[j];
#pragma unroll
    for (int p = 0; p < 8; ++p) acc[p] = b2j;
  }
  const float4* w2r = (const float4*)(W2 + j * S_);
#pragma unroll
  for (int k4 = 0; k4 < S_ / 4; ++k4) {
    const float4 w4 = w2r[k4];
#pragma unroll
    for (int p = 0; p < 8; ++p)
      acc[p] += dot4(w4, *(const float4*)&s_h1[wv][p][k4 * 4]);
  }
  const float w3j = W3[j], b3v = b3[0];
#pragma unroll
  for (int p = 0; p < 8; ++p) {
    float pp = fmaxf(acc[p], 0.f) * w3j;
    for (int off = 32; off; off >>= 1) pp += __shfl_xor(pp, off, 64);
    if (lane == 0)
      out[g * MP_ + wv * 8 + p] = 1.f / (1.f + expf(-(pp + b3v)));
  }
}

extern "C" void kernel_launch(void* const* d_in, const int* in_sizes, int n_in,
                              void* d_out, int out_size, void* d_ws, size_t ws_size,
                              hipStream_t stream) {
  const int* concepts = (const int*)d_in[0];
  const int* interactions = (const int*)d_in[1];
  const float* Kmem = (const float*)d_in[2];
  const float* Vmem = (const float*)d_in[3];
  const float* cemb = (const float*)d_in[4];
  const float* iemb = (const float*)d_in[5];
  const float* We = (const float*)d_in[6];
  const float* be = (const float*)d_in[7];
  const float* Wa = (const float*)d_in[8];
  const float* ba = (const float*)d_in[9];
  const float* W1 = (const float*)d_in[10];
  const float* b1 = (const float*)d_in[11];
  const float* W2 = (const float*)d_in[12];
  const float* b2 = (const float*)d_in[13];
  const float* W3 = (const float*)d_in[14];
  const float* b3 = (const float*)d_in[15];
  float* out = (float*)d_out;

  const size_t sz_w = (size_t)NCID * N_ * 4;
  const size_t sz_e = (size_t)NIID * DV_ * 4;
  float* wtab = (float*)d_ws;
  float* etab = (float*)((char*)d_ws + sz_w);
  float* atab = (float*)((char*)d_ws + sz_w + sz_e);
  h16* rpart = (h16*)((char*)d_ws + sz_w + 2 * sz_e);  // 2 x 64 MiB

  kW<<<dim3(NCID), dim3(512), 0, stream>>>(Kmem, cemb, wtab);
  kG<<<dim3((NIID + 7) / 8), dim3(512), 0, stream>>>(iemb, We, be, Wa, ba, etab, atab);
  kS<<<dim3(B_ * 2), dim3(1024), 0, stream>>>(concepts, interactions, Vmem,
                                              wtab, etab, atab, rpart);
  kM<<<dim3(NP_ / MP_), dim3(512), 0, stream>>>(concepts, cemb, rpart,
                                                W1, b1, W2, b2, W3, b3, out);
}